// Round 22
// baseline (307.253 us; speedup 1.0000x reference)
//
#include <hip/hip_runtime.h>

typedef unsigned long long u64;
typedef unsigned int u32;

constexpr int TPB = 256;   // merge/expand/fallback block size
constexpr int TPA = 128;   // A-kernel block size
constexpr int T  = 50;
constexpr int M  = 512;    // batch

// ---------------------------------------------------------------------------
// A-kernel (split-K): ONE KC=512 chain partial of C = A @ W^T.
// Block tile 64x64, 128 threads, per-thread 8x4. blockIdx.z = chain.
// Per-element order: single sequential k-ascending FMA chain (r16-certified).
// ---------------------------------------------------------------------------
__global__ __launch_bounds__(TPA)
void gemm_part(const float* __restrict__ A, const int K, const int N,
               const float* __restrict__ W, float* __restrict__ pp)
{
    constexpr int BM = 64, BN = 64, BK = 64;
    __shared__ float sA[BK][BM + 4];
    __shared__ float sB[BK][BN + 4];

    const int tid = threadIdx.x;
    const int tx  = tid & 15;        // 16 col groups x 4
    const int ty  = tid >> 4;        // 8 row groups x 8
    const int n0  = blockIdx.x * BN;
    const int m0  = blockIdx.y * BM;
    const int kbase = blockIdx.z * 512;

    float S[8][4];
    #pragma unroll
    for (int i = 0; i < 8; ++i)
        #pragma unroll
        for (int j = 0; j < 4; ++j) S[i][j] = 0.0f;

    // staging: float4 index f = c*TPA + tid -> row = f/16, kcol = (f%16)*4
    // consecutive lanes read consecutive 16B chunks (fully coalesced)
    int arow[8], akc[8];
    #pragma unroll
    for (int c = 0; c < 8; ++c) {
        const int f = c * TPA + tid;
        arow[c] = f >> 4;
        akc[c]  = (f & 15) << 2;
    }

    float4 fa[8], fw[8];
    auto loadA = [&](int t) {
        #pragma unroll
        for (int c = 0; c < 8; ++c)
            fa[c] = *reinterpret_cast<const float4*>(
                A + (size_t)(m0 + arow[c]) * K + kbase + t * BK + akc[c]);
    };
    auto loadW = [&](int t) {
        #pragma unroll
        for (int c = 0; c < 8; ++c)
            fw[c] = *reinterpret_cast<const float4*>(
                W + (size_t)(n0 + arow[c]) * K + kbase + t * BK + akc[c]);
    };

    constexpr int NT = 512 / BK;   // 8 tiles per chain
    loadA(0); loadW(0);

    for (int t = 0; t < NT; ++t) {
        __syncthreads();
        #pragma unroll
        for (int c = 0; c < 8; ++c) {
            sA[akc[c] + 0][arow[c]] = fa[c].x;
            sA[akc[c] + 1][arow[c]] = fa[c].y;
            sA[akc[c] + 2][arow[c]] = fa[c].z;
            sA[akc[c] + 3][arow[c]] = fa[c].w;
            sB[akc[c] + 0][arow[c]] = fw[c].x;
            sB[akc[c] + 1][arow[c]] = fw[c].y;
            sB[akc[c] + 2][arow[c]] = fw[c].z;
            sB[akc[c] + 3][arow[c]] = fw[c].w;
        }
        __syncthreads();

        if (t + 1 < NT) { loadA(t + 1); loadW(t + 1); }

        #pragma unroll
        for (int kk = 0; kk < BK; ++kk) {
            const float4 a0 = *reinterpret_cast<const float4*>(&sA[kk][ty * 8]);
            const float4 a1 = *reinterpret_cast<const float4*>(&sA[kk][ty * 8 + 4]);
            const float4 b4 = *reinterpret_cast<const float4*>(&sB[kk][tx * 4]);
            const float a[8] = {a0.x, a0.y, a0.z, a0.w, a1.x, a1.y, a1.z, a1.w};
            const float b[4] = {b4.x, b4.y, b4.z, b4.w};
            #pragma unroll
            for (int i = 0; i < 8; ++i)
                #pragma unroll
                for (int j = 0; j < 4; ++j)
                    S[i][j] = __fmaf_rn(a[i], b[j], S[i][j]);
        }
    }

    float* dst = pp + (size_t)blockIdx.z * M * N;
    #pragma unroll
    for (int i = 0; i < 8; ++i) {
        const size_t off = (size_t)(m0 + ty * 8 + i) * N + (n0 + tx * 4);
        *reinterpret_cast<float4*>(dst + off) =
            make_float4(S[i][0], S[i][1], S[i][2], S[i][3]);
    }
}

// ---------------------------------------------------------------------------
// Merge chains (ordered fadd), + bias, LIF, emit mean floats (optional),
// then expand spikes (block = 256 consecutive neurons, streaming writes).
// ---------------------------------------------------------------------------
template<bool DUP, bool WMEAN>
__global__ __launch_bounds__(TPB)
void merge_lif_expand(const float* __restrict__ pp, const int nchain,
                      const int N, const float* __restrict__ bias,
                      float* __restrict__ meanOut, float* __restrict__ out,
                      float* __restrict__ dup)
{
    __shared__ u64 lm[TPB];
    const int tid = threadIdx.x;
    const size_t base = (size_t)blockIdx.x * TPB;
    const size_t idx  = base + tid;
    const size_t cs   = (size_t)M * N;

    float s = pp[idx];
    for (int c = 1; c < nchain; ++c) s = __fadd_rn(s, pp[(size_t)c * cs + idx]);
    const float I = __fadd_rn(s, bias[idx & (size_t)(N - 1)]);

    float V = 0.0f; u64 msk = 0ull;
    #pragma unroll 1
    for (int t = 0; t < T; ++t) {
        V = __fadd_rn(__fmul_rn(V, 0.9f), I);
        if (V > 1.0f) { V = 0.0f; msk |= (1ull << t); }
    }
    if constexpr (WMEAN)
        meanOut[idx] = __fdiv_rn((float)__popcll(msk), 50.0f);
    lm[tid] = msk;
    __syncthreads();

    constexpr int TOTQ = TPB * T / 4;   // 3200 float4s
    for (int q4 = tid; q4 < TOTQ; q4 += TPB) {
        const int q = q4 << 2;
        int nn = q / T;
        int tt = q - nn * T;
        u64 mk = lm[nn];
        float vals[4];
        #pragma unroll
        for (int c = 0; c < 4; ++c) {
            if (tt >= T) { tt -= T; ++nn; mk = lm[nn]; }
            vals[c] = (float)((mk >> tt) & 1ull);
            ++tt;
        }
        const float4 v4 = make_float4(vals[0], vals[1], vals[2], vals[3]);
        const size_t off = base * T + q;
        *reinterpret_cast<float4*>(out + off) = v4;
        if constexpr (DUP) *reinterpret_cast<float4*>(dup + off) = v4;
    }
}

// ---------------------------------------------------------------------------
// Fallback (r19-proven): fused GEMM+LIF->mask kernel + expand kernels.
// ---------------------------------------------------------------------------
template<bool IN_MASK>
__global__ __launch_bounds__(TPB)
void lif_gemm_mask(const void* __restrict__ Ain, const int K, const int N,
                   const float* __restrict__ W, const float* __restrict__ bias,
                   u64* __restrict__ maskOut)
{
    constexpr int BM = 64, BN = 64, BK = 64;
    __shared__ float sA[BK][BM + 4];
    __shared__ float sB[BK][BN + 4];
    const int tid = threadIdx.x;
    const int tx = tid & 15, ty = tid >> 4;
    const int n0 = blockIdx.x * BN, m0 = blockIdx.y * BM;
    const int lr = tid >> 2, klc = (tid & 3) << 4;

    float S[4][4], Ia[4][4];
    #pragma unroll
    for (int i = 0; i < 4; ++i)
        #pragma unroll
        for (int j = 0; j < 4; ++j) { S[i][j] = 0.0f; Ia[i][j] = 0.0f; }

    const float* aF = (const float*)Ain + (size_t)(m0 + lr) * K + klc;
    const u64*   aM = (const u64*)Ain   + (size_t)(m0 + lr) * K + klc;
    const float* wp = W + (size_t)(n0 + lr) * K + klc;
    float4 fa[4]; uint4 ma[8]; float4 fw[4];

    auto loadA = [&](int k0) {
        if constexpr (IN_MASK) {
            const uint4* p = reinterpret_cast<const uint4*>(aM + k0);
            #pragma unroll
            for (int c = 0; c < 8; ++c) ma[c] = p[c];
        } else {
            #pragma unroll
            for (int c = 0; c < 4; ++c)
                fa[c] = *reinterpret_cast<const float4*>(aF + k0 + 4 * c);
        }
    };
    auto loadW = [&](int k0) {
        #pragma unroll
        for (int c = 0; c < 4; ++c)
            fw[c] = *reinterpret_cast<const float4*>(wp + k0 + 4 * c);
    };

    const int NT = K / BK;
    loadA(0); loadW(0);
    for (int t = 0; t < NT; ++t) {
        __syncthreads();
        if constexpr (IN_MASK) {
            #pragma unroll
            for (int i = 0; i < 16; ++i) {
                const u32 lo = (i & 1) ? ma[i >> 1].z : ma[i >> 1].x;
                const u32 hi = (i & 1) ? ma[i >> 1].w : ma[i >> 1].y;
                sA[klc + i][lr] = __fdiv_rn((float)(__popc(lo) + __popc(hi)), 50.0f);
            }
        } else {
            #pragma unroll
            for (int c = 0; c < 4; ++c) {
                sA[klc + 4 * c + 0][lr] = fa[c].x;
                sA[klc + 4 * c + 1][lr] = fa[c].y;
                sA[klc + 4 * c + 2][lr] = fa[c].z;
                sA[klc + 4 * c + 3][lr] = fa[c].w;
            }
        }
        #pragma unroll
        for (int c = 0; c < 4; ++c) {
            sB[klc + 4 * c + 0][lr] = fw[c].x;
            sB[klc + 4 * c + 1][lr] = fw[c].y;
            sB[klc + 4 * c + 2][lr] = fw[c].z;
            sB[klc + 4 * c + 3][lr] = fw[c].w;
        }
        __syncthreads();
        if (t + 1 < NT) { loadA((t + 1) * BK); loadW((t + 1) * BK); }
        #pragma unroll
        for (int kk = 0; kk < BK; ++kk) {
            const float4 a4 = *reinterpret_cast<const float4*>(&sA[kk][ty * 4]);
            const float4 b4 = *reinterpret_cast<const float4*>(&sB[kk][tx * 4]);
            const float a[4] = {a4.x, a4.y, a4.z, a4.w};
            const float b[4] = {b4.x, b4.y, b4.z, b4.w};
            #pragma unroll
            for (int i = 0; i < 4; ++i)
                #pragma unroll
                for (int j = 0; j < 4; ++j)
                    S[i][j] = __fmaf_rn(a[i], b[j], S[i][j]);
        }
        if ((((t + 1) * BK) & 511) == 0) {
            #pragma unroll
            for (int i = 0; i < 4; ++i)
                #pragma unroll
                for (int j = 0; j < 4; ++j) {
                    Ia[i][j] = __fadd_rn(Ia[i][j], S[i][j]);
                    S[i][j]  = 0.0f;
                }
        }
    }
    #pragma unroll
    for (int i = 0; i < 4; ++i)
        #pragma unroll
        for (int j = 0; j < 4; ++j) {
            const int mi = ty * 4 + i, nj = tx * 4 + j;
            const float I = __fadd_rn(Ia[i][j], bias[n0 + nj]);
            float V = 0.0f; u64 msk = 0ull;
            #pragma unroll 1
            for (int t = 0; t < T; ++t) {
                V = __fadd_rn(__fmul_rn(V, 0.9f), I);
                if (V > 1.0f) { V = 0.0f; msk |= (1ull << t); }
            }
            maskOut[(size_t)(m0 + mi) * N + (n0 + nj)] = msk;
        }
}

template<bool DUP>
__global__ __launch_bounds__(TPB)
void expand_spikes(const u64* __restrict__ mask, float* __restrict__ out,
                   float* __restrict__ dup)
{
    __shared__ u64 lm[TPB];
    const int tid = threadIdx.x;
    const size_t base = (size_t)blockIdx.x * TPB;
    lm[tid] = mask[base + tid];
    __syncthreads();
    constexpr int TOTQ = TPB * T / 4;
    for (int q4 = tid; q4 < TOTQ; q4 += TPB) {
        const int q = q4 << 2;
        int nn = q / T, tt = q - nn * T;
        u64 mk = lm[nn];
        float vals[4];
        #pragma unroll
        for (int c = 0; c < 4; ++c) {
            if (tt >= T) { tt -= T; ++nn; mk = lm[nn]; }
            vals[c] = (float)((mk >> tt) & 1ull);
            ++tt;
        }
        const float4 v4 = make_float4(vals[0], vals[1], vals[2], vals[3]);
        const size_t off = base * T + q;
        *reinterpret_cast<float4*>(out + off) = v4;
        if constexpr (DUP) *reinterpret_cast<float4*>(dup + off) = v4;
    }
}

extern "C" void kernel_launch(void* const* d_in, const int* in_sizes, int n_in,
                              void* d_out, int out_size, void* d_ws, size_t ws_size,
                              hipStream_t stream) {
    const float* x  = (const float*)d_in[0];
    const float* W0 = (const float*)d_in[1];
    const float* b0 = (const float*)d_in[2];
    const float* W1 = (const float*)d_in[3];
    const float* b1 = (const float*)d_in[4];
    const float* W2 = (const float*)d_in[5];
    const float* b2 = (const float*)d_in[6];
    float* out = (float*)d_out;

    constexpr int H = 2048, DOUT = 1024;
    const size_t s2sz = (size_t)M * DOUT * T;
    const size_t s0sz = (size_t)M * H * T;
    const size_t NH = (size_t)M * H;       // 1,048,576
    const size_t ND = (size_t)M * DOUT;    // 524,288

    // d_out layout (f32, r13/r17-proven): [s2a | s0 | s1 | s2b]
    float* s2a = out;
    float* s0  = out + s2sz;
    float* s1  = s0 + s0sz;
    float* s2b = s1 + s0sz;

    dim3 blkA(TPA), blk(TPB);
    const size_t WS_NEED = (2 * NH + 4 * NH + 4 * ND + 2 * NH) * sizeof(float);

    if (ws_size >= WS_NEED) {
        float* pp0   = (float*)d_ws;          // 2 chains x NH
        float* pp1   = pp0 + 2 * NH;          // 4 chains x NH
        float* pp2   = pp1 + 4 * NH;          // 4 chains x ND
        float* mean0 = pp2 + 4 * ND;          // NH floats
        float* mean1 = mean0 + NH;            // NH floats

        gemm_part<<<dim3(H / 64, M / 64, 2), blkA, 0, stream>>>(
            x, 1024, H, W0, pp0);
        merge_lif_expand<false, true><<<(int)(NH / TPB), blk, 0, stream>>>(
            pp0, 2, H, b0, mean0, s0, nullptr);
        gemm_part<<<dim3(H / 64, M / 64, 4), blkA, 0, stream>>>(
            mean0, H, H, W1, pp1);
        merge_lif_expand<false, true><<<(int)(NH / TPB), blk, 0, stream>>>(
            pp1, 4, H, b1, mean1, s1, nullptr);
        gemm_part<<<dim3(DOUT / 64, M / 64, 4), blkA, 0, stream>>>(
            mean1, H, DOUT, W2, pp2);
        merge_lif_expand<true, false><<<(int)(ND / TPB), blk, 0, stream>>>(
            pp2, 4, DOUT, b2, nullptr, s2b, s2a);
    } else {
        // r19-proven fallback: masks in d_out stashes + d_ws
        u64* mask0 = (u64*)s1;
        u64* mask1 = (u64*)s2a;
        u64* mask2 = (u64*)d_ws;
        dim3 gH(H / 64, M / 64), gD(DOUT / 64, M / 64);
        lif_gemm_mask<false><<<gH, blk, 0, stream>>>(x, 1024, H, W0, b0, mask0);
        lif_gemm_mask<true ><<<gH, blk, 0, stream>>>(mask0, H, H, W1, b1, mask1);
        lif_gemm_mask<true ><<<gD, blk, 0, stream>>>(mask1, H, DOUT, W2, b2, mask2);
        expand_spikes<false><<<(int)(NH / TPB), blk, 0, stream>>>(mask0, s0, nullptr);
        expand_spikes<false><<<(int)(NH / TPB), blk, 0, stream>>>(mask1, s1, nullptr);
        expand_spikes<true ><<<(int)(ND / TPB), blk, 0, stream>>>(mask2, s2b, s2a);
    }
}

// Round 23
// 276.955 us; speedup vs baseline: 1.1094x; 1.1094x over previous
//
#include <hip/hip_runtime.h>

typedef unsigned long long u64;
typedef unsigned int u32;

constexpr int TPB = 256;
constexpr int T  = 50;
constexpr int M  = 512;    // batch

// ---------------------------------------------------------------------------
// Combined kernel: blocks [0, gemmBlocks) run a split-K GEMM partial
// (r21-proven shape: 128x64 tile, 256 threads, 8x4/thread, one KC=512 chain
// per block, sequential k-ascending FMA chain — r16-certified order);
// blocks [gemmBlocks, ...) expand u64 spike masks into f32 spike trains
// (256 neurons/block, coalesced float4 streaming writes).
// ---------------------------------------------------------------------------
template<bool DUP>
__global__ __launch_bounds__(TPB)
void gemm_expand(const float* __restrict__ A, const int K, const int N,
                 const float* __restrict__ W, float* __restrict__ pp,
                 const int gemmBlocks, const int gx, const int gy,
                 const u64* __restrict__ mask, float* __restrict__ out,
                 float* __restrict__ dup)
{
    __shared__ float sA[64][128 + 4];
    __shared__ float sB[64][64 + 4];
    __shared__ u64   lm[TPB];

    const int tid = threadIdx.x;
    const int bid = blockIdx.x;

    if (bid < gemmBlocks) {
        // ---- GEMM role (r21 body) ----
        const int x = bid % gx;
        const int r = bid / gx;
        const int y = r % gy;
        const int z = r / gy;

        const int tx = tid & 15;         // 16 col groups x 4
        const int ty = tid >> 4;         // 16 row groups x 8
        const int n0 = x * 64;
        const int m0 = y * 128;
        const int kbase = z * 512;

        const int ar = tid >> 1, aks = (tid & 1) << 5;
        const int wr = tid >> 2, wks = (tid & 3) << 4;

        float S[8][4];
        #pragma unroll
        for (int i = 0; i < 8; ++i)
            #pragma unroll
            for (int j = 0; j < 4; ++j) S[i][j] = 0.0f;

        const float* aP = A + (size_t)(m0 + ar) * K + kbase + aks;
        const float* wP = W + (size_t)(n0 + wr) * K + kbase + wks;

        float4 fa[8], fw[4];
        auto loadA = [&](int t) {
            #pragma unroll
            for (int c = 0; c < 8; ++c)
                fa[c] = *reinterpret_cast<const float4*>(aP + t * 64 + 4 * c);
        };
        auto loadW = [&](int t) {
            #pragma unroll
            for (int c = 0; c < 4; ++c)
                fw[c] = *reinterpret_cast<const float4*>(wP + t * 64 + 4 * c);
        };

        constexpr int NT = 512 / 64;
        loadA(0); loadW(0);

        for (int t = 0; t < NT; ++t) {
            __syncthreads();
            #pragma unroll
            for (int c = 0; c < 8; ++c) {
                sA[aks + 4 * c + 0][ar] = fa[c].x;
                sA[aks + 4 * c + 1][ar] = fa[c].y;
                sA[aks + 4 * c + 2][ar] = fa[c].z;
                sA[aks + 4 * c + 3][ar] = fa[c].w;
            }
            #pragma unroll
            for (int c = 0; c < 4; ++c) {
                sB[wks + 4 * c + 0][wr] = fw[c].x;
                sB[wks + 4 * c + 1][wr] = fw[c].y;
                sB[wks + 4 * c + 2][wr] = fw[c].z;
                sB[wks + 4 * c + 3][wr] = fw[c].w;
            }
            __syncthreads();

            if (t + 1 < NT) { loadA(t + 1); loadW(t + 1); }

            #pragma unroll
            for (int kk = 0; kk < 64; ++kk) {
                const float4 a0 = *reinterpret_cast<const float4*>(&sA[kk][ty * 8]);
                const float4 a1 = *reinterpret_cast<const float4*>(&sA[kk][ty * 8 + 4]);
                const float4 b4 = *reinterpret_cast<const float4*>(&sB[kk][tx * 4]);
                const float a[8] = {a0.x, a0.y, a0.z, a0.w, a1.x, a1.y, a1.z, a1.w};
                const float b[4] = {b4.x, b4.y, b4.z, b4.w};
                #pragma unroll
                for (int i = 0; i < 8; ++i)
                    #pragma unroll
                    for (int j = 0; j < 4; ++j)
                        S[i][j] = __fmaf_rn(a[i], b[j], S[i][j]);
            }
        }

        float* dst = pp + (size_t)z * M * N;
        #pragma unroll
        for (int i = 0; i < 8; ++i) {
            const size_t off = (size_t)(m0 + ty * 8 + i) * N + (n0 + tx * 4);
            *reinterpret_cast<float4*>(dst + off) =
                make_float4(S[i][0], S[i][1], S[i][2], S[i][3]);
        }
    } else {
        // ---- expander role ----
        const size_t base = (size_t)(bid - gemmBlocks) * TPB;
        lm[tid] = mask[base + tid];
        __syncthreads();

        constexpr int TOTQ = TPB * T / 4;   // 3200 float4s
        for (int q4 = tid; q4 < TOTQ; q4 += TPB) {
            const int q = q4 << 2;
            int nn = q / T;
            int tt = q - nn * T;
            u64 mk = lm[nn];
            float vals[4];
            #pragma unroll
            for (int c = 0; c < 4; ++c) {
                if (tt >= T) { tt -= T; ++nn; mk = lm[nn]; }
                vals[c] = (float)((mk >> tt) & 1ull);
                ++tt;
            }
            const float4 v4 = make_float4(vals[0], vals[1], vals[2], vals[3]);
            const size_t off = base * T + q;
            *reinterpret_cast<float4*>(out + off) = v4;
            if constexpr (DUP) *reinterpret_cast<float4*>(dup + off) = v4;
        }
    }
}

// ---------------------------------------------------------------------------
// meanify: merge chain partials (ordered fadd), + bias, LIF -> u64 mask
// (+ optional mean = fdiv(popcount, 50)). Light traffic (~20 MB).
// ---------------------------------------------------------------------------
__global__ __launch_bounds__(TPB)
void meanify(const float* __restrict__ pp, const int nchain, const int N,
             const float* __restrict__ bias, u64* __restrict__ maskOut,
             float* __restrict__ meanOut)
{
    const size_t idx = (size_t)blockIdx.x * TPB + threadIdx.x;
    const size_t cs  = (size_t)M * N;

    float s = pp[idx];
    for (int c = 1; c < nchain; ++c) s = __fadd_rn(s, pp[(size_t)c * cs + idx]);
    const float I = __fadd_rn(s, bias[idx & (size_t)(N - 1)]);

    float V = 0.0f; u64 msk = 0ull;
    #pragma unroll 1
    for (int t = 0; t < T; ++t) {
        V = __fadd_rn(__fmul_rn(V, 0.9f), I);
        if (V > 1.0f) { V = 0.0f; msk |= (1ull << t); }
    }
    maskOut[idx] = msk;
    if (meanOut != nullptr)
        meanOut[idx] = __fdiv_rn((float)__popcll(msk), 50.0f);
}

// ---------------------------------------------------------------------------
// Standalone expander (for the final layer, with duplicate write).
// ---------------------------------------------------------------------------
template<bool DUP>
__global__ __launch_bounds__(TPB)
void expand_spikes(const u64* __restrict__ mask, float* __restrict__ out,
                   float* __restrict__ dup)
{
    __shared__ u64 lm[TPB];
    const int tid = threadIdx.x;
    const size_t base = (size_t)blockIdx.x * TPB;
    lm[tid] = mask[base + tid];
    __syncthreads();
    constexpr int TOTQ = TPB * T / 4;
    for (int q4 = tid; q4 < TOTQ; q4 += TPB) {
        const int q = q4 << 2;
        int nn = q / T, tt = q - nn * T;
        u64 mk = lm[nn];
        float vals[4];
        #pragma unroll
        for (int c = 0; c < 4; ++c) {
            if (tt >= T) { tt -= T; ++nn; mk = lm[nn]; }
            vals[c] = (float)((mk >> tt) & 1ull);
            ++tt;
        }
        const float4 v4 = make_float4(vals[0], vals[1], vals[2], vals[3]);
        const size_t off = base * T + q;
        *reinterpret_cast<float4*>(out + off) = v4;
        if constexpr (DUP) *reinterpret_cast<float4*>(dup + off) = v4;
    }
}

// ---------------------------------------------------------------------------
// Fallback (r19-proven): fused GEMM+LIF->mask kernel (full-K per block).
// ---------------------------------------------------------------------------
template<bool IN_MASK>
__global__ __launch_bounds__(TPB)
void lif_gemm_mask(const void* __restrict__ Ain, const int K, const int N,
                   const float* __restrict__ W, const float* __restrict__ bias,
                   u64* __restrict__ maskOut)
{
    constexpr int BM = 64, BN = 64, BK = 64;
    __shared__ float sA[BK][BM + 4];
    __shared__ float sB[BK][BN + 4];
    const int tid = threadIdx.x;
    const int tx = tid & 15, ty = tid >> 4;
    const int n0 = blockIdx.x * BN, m0 = blockIdx.y * BM;
    const int lr = tid >> 2, klc = (tid & 3) << 4;

    float S[4][4], Ia[4][4];
    #pragma unroll
    for (int i = 0; i < 4; ++i)
        #pragma unroll
        for (int j = 0; j < 4; ++j) { S[i][j] = 0.0f; Ia[i][j] = 0.0f; }

    const float* aF = (const float*)Ain + (size_t)(m0 + lr) * K + klc;
    const u64*   aM = (const u64*)Ain   + (size_t)(m0 + lr) * K + klc;
    const float* wp = W + (size_t)(n0 + lr) * K + klc;
    float4 fa[4]; uint4 ma[8]; float4 fw[4];

    auto loadA = [&](int k0) {
        if constexpr (IN_MASK) {
            const uint4* p = reinterpret_cast<const uint4*>(aM + k0);
            #pragma unroll
            for (int c = 0; c < 8; ++c) ma[c] = p[c];
        } else {
            #pragma unroll
            for (int c = 0; c < 4; ++c)
                fa[c] = *reinterpret_cast<const float4*>(aF + k0 + 4 * c);
        }
    };
    auto loadW = [&](int k0) {
        #pragma unroll
        for (int c = 0; c < 4; ++c)
            fw[c] = *reinterpret_cast<const float4*>(wp + k0 + 4 * c);
    };

    const int NT = K / BK;
    loadA(0); loadW(0);
    for (int t = 0; t < NT; ++t) {
        __syncthreads();
        if constexpr (IN_MASK) {
            #pragma unroll
            for (int i = 0; i < 16; ++i) {
                const u32 lo = (i & 1) ? ma[i >> 1].z : ma[i >> 1].x;
                const u32 hi = (i & 1) ? ma[i >> 1].w : ma[i >> 1].y;
                sA[klc + i][lr] = __fdiv_rn((float)(__popc(lo) + __popc(hi)), 50.0f);
            }
        } else {
            #pragma unroll
            for (int c = 0; c < 4; ++c) {
                sA[klc + 4 * c + 0][lr] = fa[c].x;
                sA[klc + 4 * c + 1][lr] = fa[c].y;
                sA[klc + 4 * c + 2][lr] = fa[c].z;
                sA[klc + 4 * c + 3][lr] = fa[c].w;
            }
        }
        #pragma unroll
        for (int c = 0; c < 4; ++c) {
            sB[klc + 4 * c + 0][lr] = fw[c].x;
            sB[klc + 4 * c + 1][lr] = fw[c].y;
            sB[klc + 4 * c + 2][lr] = fw[c].z;
            sB[klc + 4 * c + 3][lr] = fw[c].w;
        }
        __syncthreads();
        if (t + 1 < NT) { loadA((t + 1) * BK); loadW((t + 1) * BK); }
        #pragma unroll
        for (int kk = 0; kk < BK; ++kk) {
            const float4 a4 = *reinterpret_cast<const float4*>(&sA[kk][ty * 4]);
            const float4 b4 = *reinterpret_cast<const float4*>(&sB[kk][tx * 4]);
            const float a[4] = {a4.x, a4.y, a4.z, a4.w};
            const float b[4] = {b4.x, b4.y, b4.z, b4.w};
            #pragma unroll
            for (int i = 0; i < 4; ++i)
                #pragma unroll
                for (int j = 0; j < 4; ++j)
                    S[i][j] = __fmaf_rn(a[i], b[j], S[i][j]);
        }
        if ((((t + 1) * BK) & 511) == 0) {
            #pragma unroll
            for (int i = 0; i < 4; ++i)
                #pragma unroll
                for (int j = 0; j < 4; ++j) {
                    Ia[i][j] = __fadd_rn(Ia[i][j], S[i][j]);
                    S[i][j]  = 0.0f;
                }
        }
    }
    #pragma unroll
    for (int i = 0; i < 4; ++i)
        #pragma unroll
        for (int j = 0; j < 4; ++j) {
            const int mi = ty * 4 + i, nj = tx * 4 + j;
            const float I = __fadd_rn(Ia[i][j], bias[n0 + nj]);
            float V = 0.0f; u64 msk = 0ull;
            #pragma unroll 1
            for (int t = 0; t < T; ++t) {
                V = __fadd_rn(__fmul_rn(V, 0.9f), I);
                if (V > 1.0f) { V = 0.0f; msk |= (1ull << t); }
            }
            maskOut[(size_t)(m0 + mi) * N + (n0 + nj)] = msk;
        }
}

extern "C" void kernel_launch(void* const* d_in, const int* in_sizes, int n_in,
                              void* d_out, int out_size, void* d_ws, size_t ws_size,
                              hipStream_t stream) {
    const float* x  = (const float*)d_in[0];
    const float* W0 = (const float*)d_in[1];
    const float* b0 = (const float*)d_in[2];
    const float* W1 = (const float*)d_in[3];
    const float* b1 = (const float*)d_in[4];
    const float* W2 = (const float*)d_in[5];
    const float* b2 = (const float*)d_in[6];
    float* out = (float*)d_out;

    constexpr int H = 2048, DOUT = 1024;
    const size_t s2sz = (size_t)M * DOUT * T;
    const size_t s0sz = (size_t)M * H * T;
    const size_t NH = (size_t)M * H;       // 1,048,576
    const size_t ND = (size_t)M * DOUT;    // 524,288

    // d_out layout (f32, proven): [s2a | s0 | s1 | s2b]
    float* s2a = out;
    float* s0  = out + s2sz;
    float* s1  = s0 + s0sz;
    float* s2b = s1 + s0sz;

    dim3 blk(TPB);
    // ws: pp0(2NH) pp1(4NH) pp2(4ND) mean0(NH) mean1(NH) f32 + masks u64
    const size_t WS_NEED = (8 * NH + 4 * ND) * sizeof(float)
                         + (2 * NH + ND) * sizeof(u64);   // ~60 MB

    if (ws_size >= WS_NEED) {
        float* pp0   = (float*)d_ws;
        float* pp1   = pp0 + 2 * NH;
        float* pp2   = pp1 + 4 * NH;
        float* mean0 = pp2 + 4 * ND;
        float* mean1 = mean0 + NH;
        u64*   mask0 = (u64*)(mean1 + NH);
        u64*   mask1 = mask0 + NH;
        u64*   mask2 = mask1 + NH;

        const int g0 = 32 * 4 * 2;   // A0: gx=H/64=32, gy=M/128=4, 2 chains
        const int g1 = 32 * 4 * 4;   // A1: 4 chains
        const int g2 = 16 * 4 * 4;   // A2: gx=DOUT/64=16, 4 chains
        const int e01 = (int)(NH / TPB);   // 4096 expander blocks
        const int e2  = (int)(ND / TPB);   // 2048

        // A0 (no expanders yet)
        gemm_expand<false><<<g0, blk, 0, stream>>>(
            x, 1024, H, W0, pp0, g0, 32, 4, nullptr, nullptr, nullptr);
        meanify<<<(int)(NH / TPB), blk, 0, stream>>>(pp0, 2, H, b0, mask0, mean0);
        // A1 overlapped with expansion of layer-0 spikes
        gemm_expand<false><<<g1 + e01, blk, 0, stream>>>(
            mean0, 2048, H, W1, pp1, g1, 32, 4, mask0, s0, nullptr);
        meanify<<<(int)(NH / TPB), blk, 0, stream>>>(pp1, 4, H, b1, mask1, mean1);
        // A2 overlapped with expansion of layer-1 spikes
        gemm_expand<false><<<g2 + e01, blk, 0, stream>>>(
            mean1, 2048, DOUT, W2, pp2, g2, 16, 4, mask1, s1, nullptr);
        meanify<<<(int)(ND / TPB), blk, 0, stream>>>(pp2, 4, DOUT, b2, mask2, nullptr);
        // final expansion with duplicate write
        expand_spikes<true><<<e2, blk, 0, stream>>>(mask2, s2b, s2a);
    } else {
        // r19-proven fallback: masks in d_out stashes + d_ws
        u64* mask0 = (u64*)s1;
        u64* mask1 = (u64*)s2a;
        u64* mask2 = (u64*)d_ws;
        dim3 gH(H / 64, M / 64), gD(DOUT / 64, M / 64);
        lif_gemm_mask<false><<<gH, blk, 0, stream>>>(x, 1024, H, W0, b0, mask0);
        lif_gemm_mask<true ><<<gH, blk, 0, stream>>>(mask0, H, H, W1, b1, mask1);
        lif_gemm_mask<true ><<<gD, blk, 0, stream>>>(mask1, H, DOUT, W2, b2, mask2);
        expand_spikes<false><<<(int)(NH / TPB), blk, 0, stream>>>(mask0, s0, nullptr);
        expand_spikes<false><<<(int)(NH / TPB), blk, 0, stream>>>(mask1, s1, nullptr);
        expand_spikes<true ><<<(int)(ND / TPB), blk, 0, stream>>>(mask2, s2b, s2a);
    }
}

// Round 24
// 266.240 us; speedup vs baseline: 1.1540x; 1.0402x over previous
//
#include <hip/hip_runtime.h>

typedef unsigned long long u64;
typedef unsigned int u32;

constexpr int TPB = 256;
constexpr int T  = 50;
constexpr int M  = 512;    // batch

// ---------------------------------------------------------------------------
// A-kernel (split-K, double-buffered): ONE KC=512 chain partial of
// C = A @ W^T. Block tile 128x64, 256 threads, 8x4/thread, BK=32, 16 tiles
// per chain, 1 barrier/tile. Per-element order: single sequential
// k-ascending FMA chain (r16-certified; tiles asc, kk asc — unchanged).
// ---------------------------------------------------------------------------
__global__ __launch_bounds__(TPB)
void gemm_part(const float* __restrict__ A, const int K, const int N,
               const float* __restrict__ W, float* __restrict__ pp)
{
    constexpr int BK = 32, NT = 512 / BK;
    __shared__ float sA[2][BK][128 + 4];
    __shared__ float sB[2][BK][64 + 4];

    const int tid = threadIdx.x;
    const int tx  = tid & 15;        // 16 col groups x 4
    const int ty  = tid >> 4;        // 16 row groups x 8
    const int n0  = blockIdx.x * 64;
    const int m0  = blockIdx.y * 128;
    const int kbase = blockIdx.z * 512;

    // staging maps (f = c*256 + tid): row = f>>3, kq = (f&7)*4
    const int srow = tid >> 3;        // + 32*c for A
    const int skq  = (tid & 7) << 2;

    float S[8][4];
    #pragma unroll
    for (int i = 0; i < 8; ++i)
        #pragma unroll
        for (int j = 0; j < 4; ++j) S[i][j] = 0.0f;

    float4 fa[4], fw[2];
    auto loadA = [&](int t) {
        #pragma unroll
        for (int c = 0; c < 4; ++c)
            fa[c] = *reinterpret_cast<const float4*>(
                A + (size_t)(m0 + srow + 32 * c) * K + kbase + t * BK + skq);
    };
    auto loadW = [&](int t) {
        #pragma unroll
        for (int c = 0; c < 2; ++c)
            fw[c] = *reinterpret_cast<const float4*>(
                W + (size_t)(n0 + srow + 32 * c) * K + kbase + t * BK + skq);
    };

    loadA(0); loadW(0);

    for (int t = 0; t < NT; ++t) {
        const int buf = t & 1;
        // write tile t (in regs) to LDS buf — safe: last reader of this
        // buffer finished before barrier(t-1)
        #pragma unroll
        for (int c = 0; c < 4; ++c) {
            sA[buf][skq + 0][srow + 32 * c] = fa[c].x;
            sA[buf][skq + 1][srow + 32 * c] = fa[c].y;
            sA[buf][skq + 2][srow + 32 * c] = fa[c].z;
            sA[buf][skq + 3][srow + 32 * c] = fa[c].w;
        }
        #pragma unroll
        for (int c = 0; c < 2; ++c) {
            sB[buf][skq + 0][srow + 32 * c] = fw[c].x;
            sB[buf][skq + 1][srow + 32 * c] = fw[c].y;
            sB[buf][skq + 2][srow + 32 * c] = fw[c].z;
            sB[buf][skq + 3][srow + 32 * c] = fw[c].w;
        }
        if (t + 1 < NT) { loadA(t + 1); loadW(t + 1); }
        __syncthreads();

        #pragma unroll
        for (int kk = 0; kk < BK; ++kk) {
            const float4 a0 = *reinterpret_cast<const float4*>(&sA[buf][kk][ty * 8]);
            const float4 a1 = *reinterpret_cast<const float4*>(&sA[buf][kk][ty * 8 + 4]);
            const float4 b4 = *reinterpret_cast<const float4*>(&sB[buf][kk][tx * 4]);
            const float a[8] = {a0.x, a0.y, a0.z, a0.w, a1.x, a1.y, a1.z, a1.w};
            const float b[4] = {b4.x, b4.y, b4.z, b4.w};
            #pragma unroll
            for (int i = 0; i < 8; ++i)
                #pragma unroll
                for (int j = 0; j < 4; ++j)
                    S[i][j] = __fmaf_rn(a[i], b[j], S[i][j]);
        }
    }

    float* dst = pp + (size_t)blockIdx.z * M * N;
    #pragma unroll
    for (int i = 0; i < 8; ++i) {
        const size_t off = (size_t)(m0 + ty * 8 + i) * N + (n0 + tx * 4);
        *reinterpret_cast<float4*>(dst + off) =
            make_float4(S[i][0], S[i][1], S[i][2], S[i][3]);
    }
}

// ---------------------------------------------------------------------------
// Merge chains (ordered fadd), + bias, LIF, emit mean floats (optional),
// then expand spikes (block = 256 consecutive neurons, streaming writes).
// ---------------------------------------------------------------------------
template<bool DUP, bool WMEAN>
__global__ __launch_bounds__(TPB)
void merge_lif_expand(const float* __restrict__ pp, const int nchain,
                      const int N, const float* __restrict__ bias,
                      float* __restrict__ meanOut, float* __restrict__ out,
                      float* __restrict__ dup)
{
    __shared__ u64 lm[TPB];
    const int tid = threadIdx.x;
    const size_t base = (size_t)blockIdx.x * TPB;
    const size_t idx  = base + tid;
    const size_t cs   = (size_t)M * N;

    float s = pp[idx];
    for (int c = 1; c < nchain; ++c) s = __fadd_rn(s, pp[(size_t)c * cs + idx]);
    const float I = __fadd_rn(s, bias[idx & (size_t)(N - 1)]);

    float V = 0.0f; u64 msk = 0ull;
    #pragma unroll 1
    for (int t = 0; t < T; ++t) {
        V = __fadd_rn(__fmul_rn(V, 0.9f), I);
        if (V > 1.0f) { V = 0.0f; msk |= (1ull << t); }
    }
    if constexpr (WMEAN)
        meanOut[idx] = __fdiv_rn((float)__popcll(msk), 50.0f);
    lm[tid] = msk;
    __syncthreads();

    constexpr int TOTQ = TPB * T / 4;   // 3200 float4s
    for (int q4 = tid; q4 < TOTQ; q4 += TPB) {
        const int q = q4 << 2;
        int nn = q / T;
        int tt = q - nn * T;
        u64 mk = lm[nn];
        float vals[4];
        #pragma unroll
        for (int c = 0; c < 4; ++c) {
            if (tt >= T) { tt -= T; ++nn; mk = lm[nn]; }
            vals[c] = (float)((mk >> tt) & 1ull);
            ++tt;
        }
        const float4 v4 = make_float4(vals[0], vals[1], vals[2], vals[3]);
        const size_t off = base * T + q;
        *reinterpret_cast<float4*>(out + off) = v4;
        if constexpr (DUP) *reinterpret_cast<float4*>(dup + off) = v4;
    }
}

// ---------------------------------------------------------------------------
// Fallback (r19-proven): fused GEMM+LIF->mask kernel + expand kernels.
// ---------------------------------------------------------------------------
template<bool IN_MASK>
__global__ __launch_bounds__(TPB)
void lif_gemm_mask(const void* __restrict__ Ain, const int K, const int N,
                   const float* __restrict__ W, const float* __restrict__ bias,
                   u64* __restrict__ maskOut)
{
    constexpr int BM = 64, BN = 64, BK = 64;
    __shared__ float sA[BK][BM + 4];
    __shared__ float sB[BK][BN + 4];
    const int tid = threadIdx.x;
    const int tx = tid & 15, ty = tid >> 4;
    const int n0 = blockIdx.x * BN, m0 = blockIdx.y * BM;
    const int lr = tid >> 2, klc = (tid & 3) << 4;

    float S[4][4], Ia[4][4];
    #pragma unroll
    for (int i = 0; i < 4; ++i)
        #pragma unroll
        for (int j = 0; j < 4; ++j) { S[i][j] = 0.0f; Ia[i][j] = 0.0f; }

    const float* aF = (const float*)Ain + (size_t)(m0 + lr) * K + klc;
    const u64*   aM = (const u64*)Ain   + (size_t)(m0 + lr) * K + klc;
    const float* wp = W + (size_t)(n0 + lr) * K + klc;
    float4 fa[4]; uint4 ma[8]; float4 fw[4];

    auto loadA = [&](int k0) {
        if constexpr (IN_MASK) {
            const uint4* p = reinterpret_cast<const uint4*>(aM + k0);
            #pragma unroll
            for (int c = 0; c < 8; ++c) ma[c] = p[c];
        } else {
            #pragma unroll
            for (int c = 0; c < 4; ++c)
                fa[c] = *reinterpret_cast<const float4*>(aF + k0 + 4 * c);
        }
    };
    auto loadW = [&](int k0) {
        #pragma unroll
        for (int c = 0; c < 4; ++c)
            fw[c] = *reinterpret_cast<const float4*>(wp + k0 + 4 * c);
    };

    const int NT = K / BK;
    loadA(0); loadW(0);
    for (int t = 0; t < NT; ++t) {
        __syncthreads();
        if constexpr (IN_MASK) {
            #pragma unroll
            for (int i = 0; i < 16; ++i) {
                const u32 lo = (i & 1) ? ma[i >> 1].z : ma[i >> 1].x;
                const u32 hi = (i & 1) ? ma[i >> 1].w : ma[i >> 1].y;
                sA[klc + i][lr] = __fdiv_rn((float)(__popc(lo) + __popc(hi)), 50.0f);
            }
        } else {
            #pragma unroll
            for (int c = 0; c < 4; ++c) {
                sA[klc + 4 * c + 0][lr] = fa[c].x;
                sA[klc + 4 * c + 1][lr] = fa[c].y;
                sA[klc + 4 * c + 2][lr] = fa[c].z;
                sA[klc + 4 * c + 3][lr] = fa[c].w;
            }
        }
        #pragma unroll
        for (int c = 0; c < 4; ++c) {
            sB[klc + 4 * c + 0][lr] = fw[c].x;
            sB[klc + 4 * c + 1][lr] = fw[c].y;
            sB[klc + 4 * c + 2][lr] = fw[c].z;
            sB[klc + 4 * c + 3][lr] = fw[c].w;
        }
        __syncthreads();
        if (t + 1 < NT) { loadA((t + 1) * BK); loadW((t + 1) * BK); }
        #pragma unroll
        for (int kk = 0; kk < BK; ++kk) {
            const float4 a4 = *reinterpret_cast<const float4*>(&sA[kk][ty * 4]);
            const float4 b4 = *reinterpret_cast<const float4*>(&sB[kk][tx * 4]);
            const float a[4] = {a4.x, a4.y, a4.z, a4.w};
            const float b[4] = {b4.x, b4.y, b4.z, b4.w};
            #pragma unroll
            for (int i = 0; i < 4; ++i)
                #pragma unroll
                for (int j = 0; j < 4; ++j)
                    S[i][j] = __fmaf_rn(a[i], b[j], S[i][j]);
        }
        if ((((t + 1) * BK) & 511) == 0) {
            #pragma unroll
            for (int i = 0; i < 4; ++i)
                #pragma unroll
                for (int j = 0; j < 4; ++j) {
                    Ia[i][j] = __fadd_rn(Ia[i][j], S[i][j]);
                    S[i][j]  = 0.0f;
                }
        }
    }
    #pragma unroll
    for (int i = 0; i < 4; ++i)
        #pragma unroll
        for (int j = 0; j < 4; ++j) {
            const int mi = ty * 4 + i, nj = tx * 4 + j;
            const float I = __fadd_rn(Ia[i][j], bias[n0 + nj]);
            float V = 0.0f; u64 msk = 0ull;
            #pragma unroll 1
            for (int t = 0; t < T; ++t) {
                V = __fadd_rn(__fmul_rn(V, 0.9f), I);
                if (V > 1.0f) { V = 0.0f; msk |= (1ull << t); }
            }
            maskOut[(size_t)(m0 + mi) * N + (n0 + nj)] = msk;
        }
}

template<bool DUP>
__global__ __launch_bounds__(TPB)
void expand_spikes(const u64* __restrict__ mask, float* __restrict__ out,
                   float* __restrict__ dup)
{
    __shared__ u64 lm[TPB];
    const int tid = threadIdx.x;
    const size_t base = (size_t)blockIdx.x * TPB;
    lm[tid] = mask[base + tid];
    __syncthreads();
    constexpr int TOTQ = TPB * T / 4;
    for (int q4 = tid; q4 < TOTQ; q4 += TPB) {
        const int q = q4 << 2;
        int nn = q / T, tt = q - nn * T;
        u64 mk = lm[nn];
        float vals[4];
        #pragma unroll
        for (int c = 0; c < 4; ++c) {
            if (tt >= T) { tt -= T; ++nn; mk = lm[nn]; }
            vals[c] = (float)((mk >> tt) & 1ull);
            ++tt;
        }
        const float4 v4 = make_float4(vals[0], vals[1], vals[2], vals[3]);
        const size_t off = base * T + q;
        *reinterpret_cast<float4*>(out + off) = v4;
        if constexpr (DUP) *reinterpret_cast<float4*>(dup + off) = v4;
    }
}

extern "C" void kernel_launch(void* const* d_in, const int* in_sizes, int n_in,
                              void* d_out, int out_size, void* d_ws, size_t ws_size,
                              hipStream_t stream) {
    const float* x  = (const float*)d_in[0];
    const float* W0 = (const float*)d_in[1];
    const float* b0 = (const float*)d_in[2];
    const float* W1 = (const float*)d_in[3];
    const float* b1 = (const float*)d_in[4];
    const float* W2 = (const float*)d_in[5];
    const float* b2 = (const float*)d_in[6];
    float* out = (float*)d_out;

    constexpr int H = 2048, DOUT = 1024;
    const size_t s2sz = (size_t)M * DOUT * T;
    const size_t s0sz = (size_t)M * H * T;
    const size_t NH = (size_t)M * H;       // 1,048,576
    const size_t ND = (size_t)M * DOUT;    // 524,288

    // d_out layout (f32, proven): [s2a | s0 | s1 | s2b]
    float* s2a = out;
    float* s0  = out + s2sz;
    float* s1  = s0 + s0sz;
    float* s2b = s1 + s0sz;

    dim3 blk(TPB);
    const size_t WS_NEED = (2 * NH + 4 * NH + 4 * ND + 2 * NH) * sizeof(float);

    if (ws_size >= WS_NEED) {
        float* pp0   = (float*)d_ws;          // 2 chains x NH
        float* pp1   = pp0 + 2 * NH;          // 4 chains x NH
        float* pp2   = pp1 + 4 * NH;          // 4 chains x ND
        float* mean0 = pp2 + 4 * ND;          // NH floats
        float* mean1 = mean0 + NH;            // NH floats

        gemm_part<<<dim3(H / 64, M / 128, 2), blk, 0, stream>>>(
            x, 1024, H, W0, pp0);
        merge_lif_expand<false, true><<<(int)(NH / TPB), blk, 0, stream>>>(
            pp0, 2, H, b0, mean0, s0, nullptr);
        gemm_part<<<dim3(H / 64, M / 128, 4), blk, 0, stream>>>(
            mean0, 2048, H, W1, pp1);
        merge_lif_expand<false, true><<<(int)(NH / TPB), blk, 0, stream>>>(
            pp1, 4, H, b1, mean1, s1, nullptr);
        gemm_part<<<dim3(DOUT / 64, M / 128, 4), blk, 0, stream>>>(
            mean1, 2048, DOUT, W2, pp2);
        merge_lif_expand<true, false><<<(int)(ND / TPB), blk, 0, stream>>>(
            pp2, 4, DOUT, b2, nullptr, s2b, s2a);
    } else {
        // r19-proven fallback: masks in d_out stashes + d_ws
        u64* mask0 = (u64*)s1;
        u64* mask1 = (u64*)s2a;
        u64* mask2 = (u64*)d_ws;
        dim3 gH(H / 64, M / 64), gD(DOUT / 64, M / 64);
        lif_gemm_mask<false><<<gH, blk, 0, stream>>>(x, 1024, H, W0, b0, mask0);
        lif_gemm_mask<true ><<<gH, blk, 0, stream>>>(mask0, H, H, W1, b1, mask1);
        lif_gemm_mask<true ><<<gD, blk, 0, stream>>>(mask1, H, DOUT, W2, b2, mask2);
        expand_spikes<false><<<(int)(NH / TPB), blk, 0, stream>>>(mask0, s0, nullptr);
        expand_spikes<false><<<(int)(NH / TPB), blk, 0, stream>>>(mask1, s1, nullptr);
        expand_spikes<true ><<<(int)(ND / TPB), blk, 0, stream>>>(mask2, s2b, s2a);
    }
}